// Round 4
// baseline (257.056 us; speedup 1.0000x reference)
//
#include <hip/hip_runtime.h>

#define BATCHES 8
#define NPTS    100000
#define NPOINT  64
#define BPB     16                    // blocks per batch
#define NTHREADS 1024
#define TPB     (BPB * NTHREADS)      // threads per batch = 16384
#define KMAX    7                     // ceil(NPTS / TPB)
#define TAILN   (NPTS - (KMAX - 1) * TPB)

// workspace layout (zeroed per call by hipMemsetAsync)
#define WS_BARY_OFF 0                                    // [B][BPB][3] double = 3072 B
#define WS_CNT_OFF  3072                                 // [B] u32
#define WS_ROW_OFF  4096                                 // [B][NPOINT][BPB][4] u64 = 262144 B
#define WS_CTRL_BYTES (WS_ROW_OFF + (size_t)BATCHES * NPOINT * BPB * 4 * 8)

// contraction-free f32 squared distance, numpy sum order (dx*dx + dy*dy) + dz*dz
__device__ __forceinline__ float sq3(float dx, float dy, float dz) {
    return __fadd_rn(__fadd_rn(__fmul_rn(dx, dx), __fmul_rn(dy, dy)), __fmul_rn(dz, dz));
}

__global__ __launch_bounds__(NTHREADS, 4)
void fps_kernel(const float* __restrict__ xyz, float* __restrict__ out,
                unsigned char* __restrict__ ws)
{
    double* baryPart = (double*)(ws + WS_BARY_OFF);
    unsigned int* cnt = (unsigned int*)(ws + WS_CNT_OFF);
    unsigned long long* rows = (unsigned long long*)(ws + WS_ROW_OFF);

    const int b    = blockIdx.x & 7;          // XCD-pin heuristic: batch = low 3 bits
    const int blk  = blockIdx.x >> 3;         // 0..15 within batch
    const int tid  = threadIdx.x;
    const int wid  = tid >> 6;
    const int lane = tid & 63;
    const int t    = blk * NTHREADS + tid;

    const float* xb = xyz + (size_t)b * NPTS * 3;

    __shared__ float centC[NPOINT][3];
    __shared__ double bred[16][3];
    __shared__ unsigned long long kcomb[16][4];   // per-wave {key, x|1, y|2, z|3}
    __shared__ float s_bc[3];

    float px[KMAX], py[KMAX], pz[KMAX], dist[KMAX];
    const int nk = (t < TAILN) ? KMAX : (KMAX - 1);

    // ---- load points into registers; double partial sums for the mean ----
    double sx = 0.0, sy = 0.0, sz = 0.0;
    #pragma unroll
    for (int k = 0; k < KMAX; k++) {
        if (k < nk) {
            int p = t + k * TPB;
            float x = xb[p * 3 + 0], y = xb[p * 3 + 1], z = xb[p * 3 + 2];
            px[k] = x; py[k] = y; pz[k] = z; dist[k] = 1e10f;
            sx += (double)x; sy += (double)y; sz += (double)z;
        }
    }
    for (int off = 32; off > 0; off >>= 1) {
        sx += __shfl_down(sx, off); sy += __shfl_down(sy, off); sz += __shfl_down(sz, off);
    }
    if (lane == 0) { bred[wid][0] = sx; bred[wid][1] = sy; bred[wid][2] = sz; }
    __syncthreads();
    if (tid == 0) {
        double ax = 0, ay = 0, az = 0;
        for (int w = 0; w < 16; w++) { ax += bred[w][0]; ay += bred[w][1]; az += bred[w][2]; }
        double* dst = baryPart + ((size_t)b * BPB + blk) * 3;
        dst[0] = ax; dst[1] = ay; dst[2] = az;
        __hip_atomic_fetch_add(&cnt[b], 1u, __ATOMIC_ACQ_REL, __HIP_MEMORY_SCOPE_AGENT);
        while (__hip_atomic_load(&cnt[b], __ATOMIC_ACQUIRE, __HIP_MEMORY_SCOPE_AGENT) < BPB)
            __builtin_amdgcn_s_sleep(2);
        double mx = 0, my = 0, mz = 0;
        for (int q = 0; q < BPB; q++) {       // deterministic fixed order
            const double* s2 = baryPart + ((size_t)b * BPB + q) * 3;
            mx += s2[0]; my += s2[1]; mz += s2[2];
        }
        s_bc[0] = (float)(mx / (double)NPTS);
        s_bc[1] = (float)(my / (double)NPTS);
        s_bc[2] = (float)(mz / (double)NPTS);
    }
    __syncthreads();
    const float bx = s_bc[0], by = s_bc[1], bz = s_bc[2];

    // ---- per-thread candidate 0: farthest from barycenter (float domain, value-tracked) ----
    float bd = -1.0f, bpx = 0.f, bpy = 0.f, bpz = 0.f; int bp = 0;
    #pragma unroll
    for (int k = 0; k < KMAX; k++) {
        if (k < nk) {
            int p = t + k * TPB;
            float d = sq3(__fsub_rn(px[k], bx), __fsub_rn(py[k], by), __fsub_rn(pz[k], bz));
            if (d > bd) { bd = d; bp = p; bpx = px[k]; bpy = py[k]; bpz = pz[k]; }
        }
    }
    unsigned long long key = (((unsigned long long)__float_as_uint(bd)) << 32)
                             | (unsigned)(0xFFFFFFFFu - (unsigned)bp);

    // ================= 64 rounds, one barrier each =================
    for (int e = 0; e < NPOINT; e++) {
        // A: wave-level xor-broadcast max; winner lane posts {key,coords} to LDS
        unsigned long long wmax = key;
        for (int m = 32; m > 0; m >>= 1) {
            unsigned long long o = __shfl_xor(wmax, m); if (o > wmax) wmax = o;
        }
        if (key == wmax) {                     // exactly one lane (keys unique)
            kcomb[wid][0] = wmax;
            kcomb[wid][1] = (((unsigned long long)__float_as_uint(bpx)) << 32) | 1ull;
            kcomb[wid][2] = (((unsigned long long)__float_as_uint(bpy)) << 32) | 2ull;
            kcomb[wid][3] = (((unsigned long long)__float_as_uint(bpz)) << 32) | 3ull;
        }
        __syncthreads();                       // B: candidates visible to wave0

        unsigned long long* row = &rows[(((size_t)b * NPOINT + e) * BPB) * 4];

        // C: wave0 combines 16 wave candidates and posts the block package
        if (wid == 0) {
            unsigned long long v = (lane < 16) ? kcomb[lane][0] : 0ull;
            unsigned long long bb = v;
            for (int m = 8; m > 0; m >>= 1) {
                unsigned long long o = __shfl_xor(bb, m, 16); if (o > bb) bb = o;
            }
            unsigned long long mask = __ballot(v == bb && lane < 16);
            int winwid = __ffsll(mask) - 1;
            if (lane < 4) {
                unsigned long long wv = kcomb[winwid][lane];
                __hip_atomic_store(&row[blk * 4 + lane], wv,
                                   __ATOMIC_RELAXED, __HIP_MEMORY_SCOPE_AGENT);
            }
        }

        // D: every wave polls the full row and extracts the global winner
        unsigned long long val;
        {
            const int w = lane & 3;
            unsigned long long* myslot = &row[lane];
            while ((val = __hip_atomic_load(myslot, __ATOMIC_RELAXED,
                                            __HIP_MEMORY_SCOPE_AGENT)) == 0ull)
                __builtin_amdgcn_s_sleep(1);
            unsigned long long kv = (w == 0) ? val : 0ull;
            for (int m = 32; m > 0; m >>= 1) {
                unsigned long long o = __shfl_xor(kv, m); if (o > kv) kv = o;
            }
            unsigned long long mask = __ballot(val == kv);   // key-word lane of winning block
            int src = __ffsll(mask) - 1;
            unsigned long long xw = __shfl(val, src + 1);
            unsigned long long yw = __shfl(val, src + 2);
            unsigned long long zw = __shfl(val, src + 3);
            const int f = (int)(0xFFFFFFFFu - (unsigned)(kv & 0xFFFFFFFFull));
            const float cx = __uint_as_float((unsigned)(xw >> 32));
            const float cy = __uint_as_float((unsigned)(yw >> 32));
            const float cz = __uint_as_float((unsigned)(zw >> 32));

            // outputs + centroid table (off critical path: wave1 only)
            if (wid == 1 && lane == 0) {
                centC[e][0] = cx; centC[e][1] = cy; centC[e][2] = cz;
                if (blk == 0) {
                    out[((size_t)b * NPOINT + e) * 3 + 0] = cx;
                    out[((size_t)b * NPOINT + e) * 3 + 1] = cy;
                    out[((size_t)b * NPOINT + e) * 3 + 2] = cz;
                    out[(size_t)BATCHES * NPOINT * 3 + b * NPOINT + e] = (float)f;
                }
            }
            if (e == NPOINT - 1) break;

            // distance update vs winner + next per-thread candidate
            bd = -1.0f; bp = 0; bpx = 0.f; bpy = 0.f; bpz = 0.f;
            #pragma unroll
            for (int k = 0; k < KMAX; k++) {
                if (k < nk) {
                    int p = t + k * TPB;
                    float d = sq3(__fsub_rn(px[k], cx), __fsub_rn(py[k], cy), __fsub_rn(pz[k], cz));
                    float nd = (p == f) ? 0.0f : fminf(dist[k], d);
                    dist[k] = nd;
                    if (nd > bd) { bd = nd; bp = p; bpx = px[k]; bpy = py[k]; bpz = pz[k]; }
                }
            }
            key = (((unsigned long long)__float_as_uint(bd)) << 32)
                  | (unsigned)(0xFFFFFFFFu - (unsigned)bp);
        }
    }
    __syncthreads();                           // publish centC to all waves

    // ---- nearest-centroid assignment (centroids in LDS) ----
    float* outClust = out + (size_t)BATCHES * NPOINT * 3 + (size_t)BATCHES * NPOINT;
    float bestd[KMAX]; int besti[KMAX];
    #pragma unroll
    for (int k = 0; k < KMAX; k++) { bestd[k] = 3.4e38f; besti[k] = 0; }
    for (int j = 0; j < NPOINT; j++) {
        float cx = centC[j][0], cy = centC[j][1], cz = centC[j][2];
        #pragma unroll
        for (int k = 0; k < KMAX; k++) {
            if (k < nk) {
                float d = sq3(__fsub_rn(px[k], cx), __fsub_rn(py[k], cy), __fsub_rn(pz[k], cz));
                if (d < bestd[k]) { bestd[k] = d; besti[k] = j; }
            }
        }
    }
    #pragma unroll
    for (int k = 0; k < KMAX; k++)
        if (k < nk) outClust[(size_t)b * NPTS + t + k * TPB] = (float)besti[k];
}

extern "C" void kernel_launch(void* const* d_in, const int* in_sizes, int n_in,
                              void* d_out, int out_size, void* d_ws, size_t ws_size,
                              hipStream_t stream) {
    const float* xyz = (const float*)d_in[0];
    float* out = (float*)d_out;
    hipMemsetAsync(d_ws, 0, WS_CTRL_BYTES, stream);
    fps_kernel<<<dim3(BATCHES * BPB), dim3(NTHREADS), 0, stream>>>(
        xyz, out, (unsigned char*)d_ws);
}

// Round 5
// 214.172 us; speedup vs baseline: 1.2002x; 1.2002x over previous
//
#include <hip/hip_runtime.h>

#define BATCHES 8
#define NPTS    100000
#define NPOINT  64
#define BPB     16                    // blocks per batch
#define NTHREADS 1024
#define TPB     (BPB * NTHREADS)      // threads per batch = 16384
#define KMAX    7                     // ceil(NPTS / TPB)
#define TAILN   (NPTS - (KMAX - 1) * TPB)

// workspace layout (zeroed per call by hipMemsetAsync)
#define WS_BARY_OFF 0                                    // [B][BPB][3] double = 3072 B
#define WS_CNT_OFF  3072                                 // [B] u32
#define WS_ROW_OFF  4096                                 // [B][NPOINT][BPB][4] u64 = 262144 B
#define WS_CTRL_BYTES (WS_ROW_OFF + (size_t)BATCHES * NPOINT * BPB * 4 * 8)

// contraction-free f32 squared distance, numpy sum order (dx*dx + dy*dy) + dz*dz
__device__ __forceinline__ float sq3(float dx, float dy, float dz) {
    return __fadd_rn(__fadd_rn(__fmul_rn(dx, dx), __fmul_rn(dy, dy)), __fmul_rn(dz, dz));
}

__global__ __launch_bounds__(NTHREADS, 4)
void fps_kernel(const float* __restrict__ xyz, float* __restrict__ out,
                unsigned char* __restrict__ ws)
{
    double* baryPart = (double*)(ws + WS_BARY_OFF);
    unsigned int* cnt = (unsigned int*)(ws + WS_CNT_OFF);
    unsigned long long* rows = (unsigned long long*)(ws + WS_ROW_OFF);

    const int b    = blockIdx.x >> 4;         // R2 mapping (champion)
    const int blk  = blockIdx.x & (BPB - 1);
    const int tid  = threadIdx.x;
    const int wid  = tid >> 6;
    const int lane = tid & 63;
    const int t    = blk * NTHREADS + tid;

    const float* xb = xyz + (size_t)b * NPTS * 3;

    __shared__ float centC[NPOINT][3];
    __shared__ double bred[16][3];
    __shared__ unsigned long long kcomb[16][5];   // {key, x|1, y|2, z|3}, pad->stride 5 (no bank conflict)
    __shared__ float s_c[3];
    __shared__ int s_far;

    float px[KMAX], py[KMAX], pz[KMAX], dist[KMAX];
    const int nk = (t < TAILN) ? KMAX : (KMAX - 1);

    // ---- load points into registers; double partial sums for the mean ----
    double sx = 0.0, sy = 0.0, sz = 0.0;
    #pragma unroll
    for (int k = 0; k < KMAX; k++) {
        if (k < nk) {
            int p = t + k * TPB;
            float x = xb[p * 3 + 0], y = xb[p * 3 + 1], z = xb[p * 3 + 2];
            px[k] = x; py[k] = y; pz[k] = z; dist[k] = 1e10f;
            sx += (double)x; sy += (double)y; sz += (double)z;
        }
    }
    for (int off = 32; off > 0; off >>= 1) {
        sx += __shfl_down(sx, off); sy += __shfl_down(sy, off); sz += __shfl_down(sz, off);
    }
    if (lane == 0) { bred[wid][0] = sx; bred[wid][1] = sy; bred[wid][2] = sz; }
    __syncthreads();
    if (tid == 0) {
        double ax = 0, ay = 0, az = 0;
        for (int w = 0; w < 16; w++) { ax += bred[w][0]; ay += bred[w][1]; az += bred[w][2]; }
        double* dst = baryPart + ((size_t)b * BPB + blk) * 3;
        dst[0] = ax; dst[1] = ay; dst[2] = az;
        __hip_atomic_fetch_add(&cnt[b], 1u, __ATOMIC_ACQ_REL, __HIP_MEMORY_SCOPE_AGENT);
        while (__hip_atomic_load(&cnt[b], __ATOMIC_ACQUIRE, __HIP_MEMORY_SCOPE_AGENT) < BPB)
            __builtin_amdgcn_s_sleep(2);
        double mx = 0, my = 0, mz = 0;
        for (int q = 0; q < BPB; q++) {       // deterministic fixed order
            const double* s2 = baryPart + ((size_t)b * BPB + q) * 3;
            mx += s2[0]; my += s2[1]; mz += s2[2];
        }
        s_c[0] = (float)(mx / (double)NPTS);
        s_c[1] = (float)(my / (double)NPTS);
        s_c[2] = (float)(mz / (double)NPTS);
    }
    __syncthreads();
    const float bx = s_c[0], by = s_c[1], bz = s_c[2];

    // ---- per-thread candidate 0: farthest from barycenter ----
    float bd = -1.0f, bpx = 0.f, bpy = 0.f, bpz = 0.f; int bp = 0;
    #pragma unroll
    for (int k = 0; k < KMAX; k++) {
        if (k < nk) {
            int p = t + k * TPB;
            float d = sq3(__fsub_rn(px[k], bx), __fsub_rn(py[k], by), __fsub_rn(pz[k], bz));
            if (d > bd) { bd = d; bp = p; bpx = px[k]; bpy = py[k]; bpz = pz[k]; }
        }
    }
    unsigned long long key = (((unsigned long long)__float_as_uint(bd)) << 32)
                             | (unsigned)(0xFFFFFFFFu - (unsigned)bp);

    // ================= 64 rounds =================
    for (int e = 0; e < NPOINT; e++) {
        // A: wave xor-reduce; winner lane posts {key,coords} to LDS
        unsigned long long wmax = key;
        for (int m = 32; m > 0; m >>= 1) {
            unsigned long long o = __shfl_xor(wmax, m); if (o > wmax) wmax = o;
        }
        if (key == wmax) {                     // exactly one lane (keys unique)
            kcomb[wid][0] = wmax;
            kcomb[wid][1] = (((unsigned long long)__float_as_uint(bpx)) << 32) | 1ull;
            kcomb[wid][2] = (((unsigned long long)__float_as_uint(bpy)) << 32) | 2ull;
            kcomb[wid][3] = (((unsigned long long)__float_as_uint(bpz)) << 32) | 3ull;
        }
        __syncthreads();                       // B: candidates visible to wave0

        // C+D: wave0 does block combine, global exchange, winner extraction
        if (wid == 0) {
            unsigned long long v = (lane < 16) ? kcomb[lane][0] : 0ull;
            unsigned long long bb = v;
            for (int m = 8; m > 0; m >>= 1) {
                unsigned long long o = __shfl_xor(bb, m, 16); if (o > bb) bb = o;
            }
            unsigned long long bmask = __ballot(v == bb && lane < 16);
            int winwid = __ffsll(bmask) - 1;
            unsigned long long* row = &rows[(((size_t)b * NPOINT + e) * BPB) * 4];
            if (lane < 4) {
                unsigned long long wv = kcomb[winwid][lane];
                __hip_atomic_store(&row[blk * 4 + lane], wv,
                                   __ATOMIC_RELAXED, __HIP_MEMORY_SCOPE_AGENT);
            }
            // poll: one word per lane (16 blocks x 4 words = 64)
            unsigned long long val;
            while ((val = __hip_atomic_load(&row[lane], __ATOMIC_RELAXED,
                                            __HIP_MEMORY_SCOPE_AGENT)) == 0ull)
                __builtin_amdgcn_s_sleep(1);
            unsigned long long kv = ((lane & 3) == 0) ? val : 0ull;
            for (int m = 32; m > 0; m >>= 1) {
                unsigned long long o = __shfl_xor(kv, m); if (o > kv) kv = o;
            }
            unsigned long long mask = __ballot(val == kv);   // key word of winning block
            int src = __ffsll(mask) - 1;
            unsigned long long xw = __shfl(val, src + 1);
            unsigned long long yw = __shfl(val, src + 2);
            unsigned long long zw = __shfl(val, src + 3);
            if (lane == 0) {
                int f = (int)(0xFFFFFFFFu - (unsigned)(kv & 0xFFFFFFFFull));
                float cx = __uint_as_float((unsigned)(xw >> 32));
                float cy = __uint_as_float((unsigned)(yw >> 32));
                float cz = __uint_as_float((unsigned)(zw >> 32));
                s_far = f; s_c[0] = cx; s_c[1] = cy; s_c[2] = cz;
                centC[e][0] = cx; centC[e][1] = cy; centC[e][2] = cz;
                if (blk == 0) {
                    out[((size_t)b * NPOINT + e) * 3 + 0] = cx;
                    out[((size_t)b * NPOINT + e) * 3 + 1] = cy;
                    out[((size_t)b * NPOINT + e) * 3 + 2] = cz;
                    out[(size_t)BATCHES * NPOINT * 3 + b * NPOINT + e] = (float)f;
                }
            }
        }
        __syncthreads();                       // E: winner published
        if (e == NPOINT - 1) break;

        const int f = s_far;
        const float cx = s_c[0], cy = s_c[1], cz = s_c[2];
        bd = -1.0f; bp = 0; bpx = 0.f; bpy = 0.f; bpz = 0.f;
        #pragma unroll
        for (int k = 0; k < KMAX; k++) {
            if (k < nk) {
                int p = t + k * TPB;
                float d = sq3(__fsub_rn(px[k], cx), __fsub_rn(py[k], cy), __fsub_rn(pz[k], cz));
                float nd = (p == f) ? 0.0f : fminf(dist[k], d);
                dist[k] = nd;
                if (nd > bd) { bd = nd; bp = p; bpx = px[k]; bpy = py[k]; bpz = pz[k]; }
            }
        }
        key = (((unsigned long long)__float_as_uint(bd)) << 32)
              | (unsigned)(0xFFFFFFFFu - (unsigned)bp);
    }

    // ---- nearest-centroid assignment (centroids in LDS) ----
    float* outClust = out + (size_t)BATCHES * NPOINT * 3 + (size_t)BATCHES * NPOINT;
    float bestd[KMAX]; int besti[KMAX];
    #pragma unroll
    for (int k = 0; k < KMAX; k++) { bestd[k] = 3.4e38f; besti[k] = 0; }
    for (int j = 0; j < NPOINT; j++) {
        float cx = centC[j][0], cy = centC[j][1], cz = centC[j][2];
        #pragma unroll
        for (int k = 0; k < KMAX; k++) {
            if (k < nk) {
                float d = sq3(__fsub_rn(px[k], cx), __fsub_rn(py[k], cy), __fsub_rn(pz[k], cz));
                if (d < bestd[k]) { bestd[k] = d; besti[k] = j; }
            }
        }
    }
    #pragma unroll
    for (int k = 0; k < KMAX; k++)
        if (k < nk) outClust[(size_t)b * NPTS + t + k * TPB] = (float)besti[k];
}

extern "C" void kernel_launch(void* const* d_in, const int* in_sizes, int n_in,
                              void* d_out, int out_size, void* d_ws, size_t ws_size,
                              hipStream_t stream) {
    const float* xyz = (const float*)d_in[0];
    float* out = (float*)d_out;
    hipMemsetAsync(d_ws, 0, WS_CTRL_BYTES, stream);
    fps_kernel<<<dim3(BATCHES * BPB), dim3(NTHREADS), 0, stream>>>(
        xyz, out, (unsigned char*)d_ws);
}

// Round 6
// 174.994 us; speedup vs baseline: 1.4689x; 1.2239x over previous
//
#include <hip/hip_runtime.h>

#define BATCHES 8
#define NPTS    100000
#define NPOINT  64
#define BPB     16                    // blocks per batch
#define NTHREADS 512                  // 8 waves/block (2 per SIMD)
#define WPB     (NTHREADS / 64)
#define TPB     (BPB * NTHREADS)      // threads per batch = 8192
#define KMAX    13                    // ceil(NPTS / TPB)
#define TAILN   (NPTS - (KMAX - 1) * TPB)   // 1696 threads get a 13th point

// workspace layout (zeroed per call by hipMemsetAsync)
#define WS_BARY_OFF 0                                    // [B][BPB][3] double = 3072 B
#define WS_CNT_OFF  3072                                 // [B] u32
#define WS_SLOT_OFF 4096                                 // [B][NPOINT][BPB] u64 = 65536 B
#define WS_CTRL_BYTES (WS_SLOT_OFF + BATCHES * NPOINT * BPB * 8)

// contraction-free f32 squared distance, numpy sum order (dx*dx + dy*dy) + dz*dz
__device__ __forceinline__ float sq3(float dx, float dy, float dz) {
    return __fadd_rn(__fadd_rn(__fmul_rn(dx, dx), __fmul_rn(dy, dy)), __fmul_rn(dz, dz));
}

__global__ __launch_bounds__(NTHREADS, 4)
void fps_kernel(const float* __restrict__ xyz, float* __restrict__ out,
                unsigned char* __restrict__ ws)
{
    double* baryPart = (double*)(ws + WS_BARY_OFF);
    unsigned int* cnt = (unsigned int*)(ws + WS_CNT_OFF);
    unsigned long long* slots = (unsigned long long*)(ws + WS_SLOT_OFF);

    const int b    = blockIdx.x & 7;          // XCD-pin: same-batch blocks -> same XCD (heuristic)
    const int blk  = blockIdx.x >> 3;         // 0..15 within batch
    const int tid  = threadIdx.x;
    const int wid  = tid >> 6;
    const int lane = tid & 63;
    const int t    = blk * NTHREADS + tid;    // 0..TPB-1 within batch

    const float* xb = xyz + (size_t)b * NPTS * 3;

    __shared__ float centC[NPOINT][3];
    __shared__ double bred[WPB][3];
    __shared__ unsigned long long kred[WPB];
    __shared__ float s_c[3];
    __shared__ int s_far;

    float px[KMAX], py[KMAX], pz[KMAX], dist[KMAX];
    const int nk = (t < TAILN) ? KMAX : (KMAX - 1);

    // ---- load points into registers; double partial sums for the mean ----
    double sx = 0.0, sy = 0.0, sz = 0.0;
    #pragma unroll
    for (int k = 0; k < KMAX; k++) {
        if (k < nk) {
            int p = t + k * TPB;
            float x = xb[p * 3 + 0], y = xb[p * 3 + 1], z = xb[p * 3 + 2];
            px[k] = x; py[k] = y; pz[k] = z; dist[k] = 1e10f;
            sx += (double)x; sy += (double)y; sz += (double)z;
        }
    }
    for (int off = 32; off > 0; off >>= 1) {
        sx += __shfl_down(sx, off); sy += __shfl_down(sy, off); sz += __shfl_down(sz, off);
    }
    if (lane == 0) { bred[wid][0] = sx; bred[wid][1] = sy; bred[wid][2] = sz; }
    __syncthreads();
    if (tid == 0) {
        double ax = 0, ay = 0, az = 0;
        for (int w = 0; w < WPB; w++) { ax += bred[w][0]; ay += bred[w][1]; az += bred[w][2]; }
        double* dst = baryPart + ((size_t)b * BPB + blk) * 3;
        dst[0] = ax; dst[1] = ay; dst[2] = az;
        __hip_atomic_fetch_add(&cnt[b], 1u, __ATOMIC_ACQ_REL, __HIP_MEMORY_SCOPE_AGENT);
        while (__hip_atomic_load(&cnt[b], __ATOMIC_ACQUIRE, __HIP_MEMORY_SCOPE_AGENT) < BPB)
            __builtin_amdgcn_s_sleep(2);
        double mx = 0, my = 0, mz = 0;
        for (int q = 0; q < BPB; q++) {       // deterministic fixed order
            const double* s2 = baryPart + ((size_t)b * BPB + q) * 3;
            mx += s2[0]; my += s2[1]; mz += s2[2];
        }
        s_c[0] = (float)(mx / (double)NPTS);
        s_c[1] = (float)(my / (double)NPTS);
        s_c[2] = (float)(mz / (double)NPTS);
    }
    __syncthreads();
    const float bx = s_c[0], by = s_c[1], bz = s_c[2];

    // ---- per-thread candidate 0: farthest from barycenter ----
    float bd = -1.0f; int bp = 0;
    #pragma unroll
    for (int k = 0; k < KMAX; k++) {
        if (k < nk) {
            int p = t + k * TPB;
            float d = sq3(__fsub_rn(px[k], bx), __fsub_rn(py[k], by), __fsub_rn(pz[k], bz));
            if (d > bd) { bd = d; bp = p; }
        }
    }
    unsigned long long key = (((unsigned long long)__float_as_uint(bd)) << 32)
                             | (unsigned)(0xFFFFFFFFu - (unsigned)bp);

    // ================= 64 rounds (R2 exchange: 16 key-only slots, wave0 polls) =================
    for (int e = 0; e < NPOINT; e++) {
        // wave reduce, lane0 posts to LDS
        unsigned long long wmax = key;
        for (int m = 32; m > 0; m >>= 1) {
            unsigned long long o = __shfl_xor(wmax, m); if (o > wmax) wmax = o;
        }
        if (lane == 0) kred[wid] = wmax;
        __syncthreads();

        if (wid == 0) {
            unsigned long long v = (lane < WPB) ? kred[lane] : 0ull;
            for (int m = 4; m > 0; m >>= 1) {
                unsigned long long o = __shfl_xor(v, m, 8); if (o > v) v = o;
            }
            unsigned long long* row = &slots[((size_t)b * NPOINT + e) * BPB];
            if (lane == 0)
                __hip_atomic_store(&row[blk], v, __ATOMIC_RELAXED, __HIP_MEMORY_SCOPE_AGENT);
            unsigned long long w = 0;
            if (lane < BPB) {
                while ((w = __hip_atomic_load(&row[lane], __ATOMIC_RELAXED,
                                              __HIP_MEMORY_SCOPE_AGENT)) == 0ull)
                    __builtin_amdgcn_s_sleep(1);
            }
            for (int m = 8; m > 0; m >>= 1) {
                unsigned long long o = __shfl_xor(w, m, 16); if (o > w) w = o;
            }
            if (lane == 0) {
                int f = (int)(0xFFFFFFFFu - (unsigned)(w & 0xFFFFFFFFull));
                float cx = xb[f * 3 + 0], cy = xb[f * 3 + 1], cz = xb[f * 3 + 2];
                s_far = f; s_c[0] = cx; s_c[1] = cy; s_c[2] = cz;
                centC[e][0] = cx; centC[e][1] = cy; centC[e][2] = cz;
                if (blk == 0) {
                    out[((size_t)b * NPOINT + e) * 3 + 0] = cx;
                    out[((size_t)b * NPOINT + e) * 3 + 1] = cy;
                    out[((size_t)b * NPOINT + e) * 3 + 2] = cz;
                    out[(size_t)BATCHES * NPOINT * 3 + b * NPOINT + e] = (float)f;
                }
            }
        }
        __syncthreads();                       // winner published
        if (e == NPOINT - 1) break;

        const int f = s_far;
        const float cx = s_c[0], cy = s_c[1], cz = s_c[2];
        bd = -1.0f; bp = 0;
        #pragma unroll
        for (int k = 0; k < KMAX; k++) {
            if (k < nk) {
                int p = t + k * TPB;
                float d = sq3(__fsub_rn(px[k], cx), __fsub_rn(py[k], cy), __fsub_rn(pz[k], cz));
                float nd = (p == f) ? 0.0f : fminf(dist[k], d);
                dist[k] = nd;
                if (nd > bd) { bd = nd; bp = p; }
            }
        }
        key = (((unsigned long long)__float_as_uint(bd)) << 32)
              | (unsigned)(0xFFFFFFFFu - (unsigned)bp);
    }

    // ---- nearest-centroid assignment (centroids in LDS) ----
    float* outClust = out + (size_t)BATCHES * NPOINT * 3 + (size_t)BATCHES * NPOINT;
    float bestd[KMAX]; int besti[KMAX];
    #pragma unroll
    for (int k = 0; k < KMAX; k++) { bestd[k] = 3.4e38f; besti[k] = 0; }
    for (int j = 0; j < NPOINT; j++) {
        float cx = centC[j][0], cy = centC[j][1], cz = centC[j][2];
        #pragma unroll
        for (int k = 0; k < KMAX; k++) {
            if (k < nk) {
                float d = sq3(__fsub_rn(px[k], cx), __fsub_rn(py[k], cy), __fsub_rn(pz[k], cz));
                if (d < bestd[k]) { bestd[k] = d; besti[k] = j; }   // strict < => first-index argmin
            }
        }
    }
    #pragma unroll
    for (int k = 0; k < KMAX; k++)
        if (k < nk) outClust[(size_t)b * NPTS + t + k * TPB] = (float)besti[k];
}

extern "C" void kernel_launch(void* const* d_in, const int* in_sizes, int n_in,
                              void* d_out, int out_size, void* d_ws, size_t ws_size,
                              hipStream_t stream) {
    const float* xyz = (const float*)d_in[0];
    float* out = (float*)d_out;
    hipMemsetAsync(d_ws, 0, WS_CTRL_BYTES, stream);
    fps_kernel<<<dim3(BATCHES * BPB), dim3(NTHREADS), 0, stream>>>(
        xyz, out, (unsigned char*)d_ws);
}

// Round 7
// 149.054 us; speedup vs baseline: 1.7246x; 1.1740x over previous
//
#include <hip/hip_runtime.h>

#define BATCHES 8
#define NPTS    100000
#define NPOINT  64
#define BPB     16                    // blocks per batch
#define NTHREADS 512                  // 8 waves/block (2 per SIMD)
#define WPB     (NTHREADS / 64)
#define TPB     (BPB * NTHREADS)      // threads per batch = 8192
#define KMAX    13                    // ceil(NPTS / TPB)
#define TAILN   (NPTS - (KMAX - 1) * TPB)

// workspace layout (zeroed per call by hipMemsetAsync)
#define WS_BARY_OFF 0                                    // [B][BPB][3] double = 3072 B
#define WS_CNT_OFF  3072                                 // [B] u32
#define WS_SLOT_OFF 4096                                 // [B][NPOINT][BPB] u64 = 65536 B
#define WS_CTRL_BYTES (WS_SLOT_OFF + BATCHES * NPOINT * BPB * 8)

// contraction-free f32 squared distance, numpy sum order (dx*dx + dy*dy) + dz*dz
__device__ __forceinline__ float sq3(float dx, float dy, float dz) {
    return __fadd_rn(__fadd_rn(__fmul_rn(dx, dx), __fmul_rn(dy, dy)), __fmul_rn(dz, dz));
}

__global__ __launch_bounds__(NTHREADS, 4)
void fps_kernel(const float* __restrict__ xyz, float* __restrict__ out,
                unsigned char* __restrict__ ws)
{
    double* baryPart = (double*)(ws + WS_BARY_OFF);
    unsigned int* cnt = (unsigned int*)(ws + WS_CNT_OFF);
    unsigned long long* slots = (unsigned long long*)(ws + WS_SLOT_OFF);

    const int b    = blockIdx.x & 7;          // XCD-pin: same-batch blocks -> same XCD (heuristic)
    const int blk  = blockIdx.x >> 3;         // 0..15 within batch
    const int tid  = threadIdx.x;
    const int wid  = tid >> 6;
    const int lane = tid & 63;
    const int t    = blk * NTHREADS + tid;    // 0..TPB-1 within batch

    const float* xb = xyz + (size_t)b * NPTS * 3;

    __shared__ double bred[WPB][3];
    __shared__ unsigned long long kred[WPB];
    __shared__ float s_c[3];
    __shared__ int s_far;

    float px[KMAX], py[KMAX], pz[KMAX], dist[KMAX];
    float bestd[KMAX]; int besti[KMAX];
    const int nk = (t < TAILN) ? KMAX : (KMAX - 1);

    // ---- load points into registers; double partial sums for the mean ----
    double sx = 0.0, sy = 0.0, sz = 0.0;
    #pragma unroll
    for (int k = 0; k < KMAX; k++) {
        if (k < nk) {
            int p = t + k * TPB;
            float x = xb[p * 3 + 0], y = xb[p * 3 + 1], z = xb[p * 3 + 2];
            px[k] = x; py[k] = y; pz[k] = z; dist[k] = 1e10f;
            bestd[k] = 3.4e38f; besti[k] = 0;
            sx += (double)x; sy += (double)y; sz += (double)z;
        }
    }
    for (int off = 32; off > 0; off >>= 1) {
        sx += __shfl_down(sx, off); sy += __shfl_down(sy, off); sz += __shfl_down(sz, off);
    }
    if (lane == 0) { bred[wid][0] = sx; bred[wid][1] = sy; bred[wid][2] = sz; }
    __syncthreads();
    if (tid == 0) {
        double ax = 0, ay = 0, az = 0;
        for (int w = 0; w < WPB; w++) { ax += bred[w][0]; ay += bred[w][1]; az += bred[w][2]; }
        double* dst = baryPart + ((size_t)b * BPB + blk) * 3;
        dst[0] = ax; dst[1] = ay; dst[2] = az;
        __hip_atomic_fetch_add(&cnt[b], 1u, __ATOMIC_ACQ_REL, __HIP_MEMORY_SCOPE_AGENT);
        while (__hip_atomic_load(&cnt[b], __ATOMIC_ACQUIRE, __HIP_MEMORY_SCOPE_AGENT) < BPB)
            __builtin_amdgcn_s_sleep(2);
        double mx = 0, my = 0, mz = 0;
        for (int q = 0; q < BPB; q++) {       // deterministic fixed order
            const double* s2 = baryPart + ((size_t)b * BPB + q) * 3;
            mx += s2[0]; my += s2[1]; mz += s2[2];
        }
        s_c[0] = (float)(mx / (double)NPTS);
        s_c[1] = (float)(my / (double)NPTS);
        s_c[2] = (float)(mz / (double)NPTS);
    }
    __syncthreads();
    const float bx = s_c[0], by = s_c[1], bz = s_c[2];

    // ---- per-thread candidate 0: farthest from barycenter ----
    float bd = -1.0f; int bp = 0;
    #pragma unroll
    for (int k = 0; k < KMAX; k++) {
        if (k < nk) {
            int p = t + k * TPB;
            float d = sq3(__fsub_rn(px[k], bx), __fsub_rn(py[k], by), __fsub_rn(pz[k], bz));
            if (d > bd) { bd = d; bp = p; }
        }
    }
    unsigned long long key = (((unsigned long long)__float_as_uint(bd)) << 32)
                             | (unsigned)(0xFFFFFFFFu - (unsigned)bp);

    // ================= 64 rounds (16 key-only slots, wave0 polls) =================
    for (int e = 0; e < NPOINT; e++) {
        // wave reduce, lane0 posts to LDS
        unsigned long long wmax = key;
        for (int m = 32; m > 0; m >>= 1) {
            unsigned long long o = __shfl_xor(wmax, m); if (o > wmax) wmax = o;
        }
        if (lane == 0) kred[wid] = wmax;
        __syncthreads();

        if (wid == 0) {
            unsigned long long v = (lane < WPB) ? kred[lane] : 0ull;
            for (int m = 4; m > 0; m >>= 1) {
                unsigned long long o = __shfl_xor(v, m, 8); if (o > v) v = o;
            }
            unsigned long long* row = &slots[((size_t)b * NPOINT + e) * BPB];
            if (lane == 0)
                __hip_atomic_store(&row[blk], v, __ATOMIC_RELAXED, __HIP_MEMORY_SCOPE_AGENT);
            unsigned long long w = 0;
            if (lane < BPB) {
                while ((w = __hip_atomic_load(&row[lane], __ATOMIC_RELAXED,
                                              __HIP_MEMORY_SCOPE_AGENT)) == 0ull) { }
            }
            for (int m = 8; m > 0; m >>= 1) {
                unsigned long long o = __shfl_xor(w, m, 16); if (o > w) w = o;
            }
            if (lane == 0) {
                int f = (int)(0xFFFFFFFFu - (unsigned)(w & 0xFFFFFFFFull));
                float cx = xb[f * 3 + 0], cy = xb[f * 3 + 1], cz = xb[f * 3 + 2];
                s_far = f; s_c[0] = cx; s_c[1] = cy; s_c[2] = cz;
                if (blk == 0) {
                    out[((size_t)b * NPOINT + e) * 3 + 0] = cx;
                    out[((size_t)b * NPOINT + e) * 3 + 1] = cy;
                    out[((size_t)b * NPOINT + e) * 3 + 2] = cz;
                    out[(size_t)BATCHES * NPOINT * 3 + b * NPOINT + e] = (float)f;
                }
            }
        }
        __syncthreads();                       // winner published
        if (e == NPOINT - 1) break;

        // distance update + assignment fold + next candidate
        const float cx = s_c[0], cy = s_c[1], cz = s_c[2];
        bd = -1.0f; bp = 0;
        #pragma unroll
        for (int k = 0; k < KMAX; k++) {
            if (k < nk) {
                float d = sq3(__fsub_rn(px[k], cx), __fsub_rn(py[k], cy), __fsub_rn(pz[k], cz));
                if (d < bestd[k]) { bestd[k] = d; besti[k] = e; }   // argmin fold (first-index)
                float nd = fminf(dist[k], d);                       // winner's d==0 exactly
                dist[k] = nd;
                int p = t + k * TPB;
                if (nd > bd) { bd = nd; bp = p; }
            }
        }
        key = (((unsigned long long)__float_as_uint(bd)) << 32)
              | (unsigned)(0xFFFFFFFFu - (unsigned)bp);
    }

    // ---- final assignment pass vs centroid 63 (loop broke before updating) ----
    {
        const float cx = s_c[0], cy = s_c[1], cz = s_c[2];
        #pragma unroll
        for (int k = 0; k < KMAX; k++) {
            if (k < nk) {
                float d = sq3(__fsub_rn(px[k], cx), __fsub_rn(py[k], cy), __fsub_rn(pz[k], cz));
                if (d < bestd[k]) { bestd[k] = d; besti[k] = NPOINT - 1; }
            }
        }
    }

    float* outClust = out + (size_t)BATCHES * NPOINT * 3 + (size_t)BATCHES * NPOINT;
    #pragma unroll
    for (int k = 0; k < KMAX; k++)
        if (k < nk) outClust[(size_t)b * NPTS + t + k * TPB] = (float)besti[k];
}

extern "C" void kernel_launch(void* const* d_in, const int* in_sizes, int n_in,
                              void* d_out, int out_size, void* d_ws, size_t ws_size,
                              hipStream_t stream) {
    const float* xyz = (const float*)d_in[0];
    float* out = (float*)d_out;
    hipMemsetAsync(d_ws, 0, WS_CTRL_BYTES, stream);
    fps_kernel<<<dim3(BATCHES * BPB), dim3(NTHREADS), 0, stream>>>(
        xyz, out, (unsigned char*)d_ws);
}